// Round 5
// baseline (71.580 us; speedup 1.0000x reference)
//
#include <hip/hip_runtime.h>
#include <hip/hip_bf16.h>

constexpr int NBATCH = 2048;   // B*T
constexpr int N      = 128;    // nodes
constexpr float INVTAU = 20.0f;   // 1/0.05
constexpr float EPSF   = 1e-8f;
constexpr float MUF    = 1.0f / 128.0f;   // mu = nu = 1/N

typedef __attribute__((ext_vector_type(8))) short short8;   // 8 x bf16 MFMA frag
typedef __attribute__((ext_vector_type(4))) float f32x4;    // MFMA accumulator

static __device__ __forceinline__ float fastrcp(float x) {
    return __builtin_amdgcn_rcpf(x);    // v_rcp_f32, ~1e-7 rel err
}
static __device__ __forceinline__ float fastsqrt(float x) {
    return __builtin_amdgcn_sqrtf(x);   // raw v_sqrt_f32 (no denormal fixup seq)
}

// LDS bf16 tile, XOR-swizzled: row r, k-elt k at ushort idx
//   r*64 + (((k>>3) ^ (r&7)) << 3) + (k&7)
// 512 threads = 8 waves; wave w owns C rows 16w..16w+15, all 128 cols.
// Lane (lx=l&15, lh=l>>4) owns rows 16w+4lh+q (q<4), cols 16tc+lx (tc<8).
// C stored packed bf16 in regs (loss is linear in C; 0.4% rel err bound).
__global__ __launch_bounds__(512, 6)   // 6 waves/EU -> 3 blocks/CU, reg cap ~84
void sinkhorn_batch(const float* __restrict__ srcg,
                    const float* __restrict__ tgtg,
                    float* __restrict__ lossg)
{
    __shared__ ushort sA[N * 64];          // src bf16, swizzled (16 KB)
    __shared__ ushort sB[N * 64];          // tgt bf16, swizzled (16 KB)
    __shared__ float sX2[N], sY2[N], sV[N];
    __shared__ float sPart[8][8][16];      // [wave][colTile][lx] partials (4 KB)
    __shared__ float sRed[8];

    const int t  = threadIdx.x;
    const int l  = t & 63;
    const int w  = t >> 6;       // wave 0..7
    const int lx = l & 15;
    const int lh = l >> 4;       // 0..3
    const int bt = blockIdx.x;

    const float4* sg4 = reinterpret_cast<const float4*>(srcg + (size_t)bt * (N * 64));
    const float4* tg4 = reinterpret_cast<const float4*>(tgtg + (size_t)bt * (N * 64));

    // ---- phase 0: stage bf16 (swizzled) + fp32 row norms, fused butterfly ----
    #pragma unroll
    for (int it = 0; it < 4; ++it) {
        int f  = t + 512 * it;    // 0..2047 float4s; 16 consecutive lanes = one row
        int r  = f >> 4;
        int d4 = f & 15;
        float4 a = sg4[f];
        float4 b = tg4[f];
        float pa = a.x * a.x + a.y * a.y + a.z * a.z + a.w * a.w;
        float pb = b.x * b.x + b.y * b.y + b.z * b.z + b.w * b.w;
        // lanes g<8 carry pa, g>=8 carry pb (one exchange), then 8-lane tree
        float x = (lx & 8) ? pb : pa;
        float y = (lx & 8) ? pa : pb;
        x += __shfl_xor(y, 8);
        x += __shfl_xor(x, 1);
        x += __shfl_xor(x, 2);
        x += __shfl_xor(x, 4);
        if ((lx & 7) == 0) ((lx & 8) ? sY2 : sX2)[r] = x;

        int idx = r * 64 + (((d4 >> 1) ^ (r & 7)) << 3) + (d4 & 1) * 4;
        union { __hip_bfloat162 h[2]; ushort4 u; } ca, cb;
        ca.h[0] = __float22bfloat162_rn(make_float2(a.x, a.y));
        ca.h[1] = __float22bfloat162_rn(make_float2(a.z, a.w));
        cb.h[0] = __float22bfloat162_rn(make_float2(b.x, b.y));
        cb.h[1] = __float22bfloat162_rn(make_float2(b.z, b.w));
        *reinterpret_cast<ushort4*>(&sA[idx]) = ca.u;
        *reinterpret_cast<ushort4*>(&sB[idx]) = cb.u;
    }
    __syncthreads();

    // ---- phase 1+2 fused: per col-tile MFMA -> C,K (acc lives 4 regs at a time) --
    float x2r[4], y2c[8];
    #pragma unroll
    for (int q = 0; q < 4; ++q) x2r[q] = sX2[16 * w + 4 * lh + q];
    #pragma unroll
    for (int tc = 0; tc < 8; ++tc) y2c[tc] = sY2[16 * tc + lx];

    short8 af0, af1;
    {
        int ra = 16 * w + lx;
        af0 = *reinterpret_cast<const short8*>(&sA[ra * 64 + (((0 + lh) ^ (ra & 7)) << 3)]);
        af1 = *reinterpret_cast<const short8*>(&sA[ra * 64 + (((4 + lh) ^ (ra & 7)) << 3)]);
    }

    float kk[8][4];
    unsigned ccp[8][2];   // packed bf16: ccp[tc][p] = (bf16(c[2p+1])<<16)|bf16(c[2p])
    #pragma unroll
    for (int tc = 0; tc < 8; ++tc) {
        int rb = 16 * tc + lx;
        short8 bf0 = *reinterpret_cast<const short8*>(&sB[rb * 64 + (((0 + lh) ^ (rb & 7)) << 3)]);
        short8 bf1 = *reinterpret_cast<const short8*>(&sB[rb * 64 + (((4 + lh) ^ (rb & 7)) << 3)]);
        f32x4 acc = (f32x4){0.f, 0.f, 0.f, 0.f};
        acc = __builtin_amdgcn_mfma_f32_16x16x32_bf16(af0, bf0, acc, 0, 0, 0);
        acc = __builtin_amdgcn_mfma_f32_16x16x32_bf16(af1, bf1, acc, 0, 0, 0);
        float cd[4];
        #pragma unroll
        for (int q = 0; q < 4; ++q) {
            float d2 = x2r[q] + y2c[tc] - 2.0f * acc[q];
            cd[q] = fastsqrt(fmaxf(d2, 0.f));
            kk[tc][q] = __expf(-INVTAU * cd[q]);
        }
        union { __hip_bfloat162 h; unsigned u; } p0, p1;
        p0.h = __float22bfloat162_rn(make_float2(cd[0], cd[1]));
        p1.h = __float22bfloat162_rn(make_float2(cd[2], cd[3]));
        ccp[tc][0] = p0.u;
        ccp[tc][1] = p1.u;
    }

    if (t < N) sV[t] = 1.0f;
    __syncthreads();

    // ---- phase 3: Sinkhorn iterations; u register-resident (butterfly = allreduce) --
    float uu[4];
    #pragma unroll
    for (int iter = 0; iter < 5; ++iter) {
        // u_i = mu / (sum_j K[i][j] v[j] + eps): reduce over cols (lx in-wave)
        float vv[8];
        #pragma unroll
        for (int tc = 0; tc < 8; ++tc) vv[tc] = sV[16 * tc + lx];
        #pragma unroll
        for (int q = 0; q < 4; ++q) {
            float p = 0.f;
            #pragma unroll
            for (int tc = 0; tc < 8; ++tc) p += kk[tc][q] * vv[tc];
            p += __shfl_xor(p, 1);
            p += __shfl_xor(p, 2);
            p += __shfl_xor(p, 4);
            p += __shfl_xor(p, 8);
            uu[q] = MUF * fastrcp(p + EPSF);   // every lane holds the full sum
        }
        // no barrier: u never touches LDS

        // v_j = nu / (sum_i K[i][j] u[i] + eps): reduce over rows
        #pragma unroll
        for (int tc = 0; tc < 8; ++tc) {
            float qc = 0.f;
            #pragma unroll
            for (int q = 0; q < 4; ++q) qc += kk[tc][q] * uu[q];
            qc += __shfl_xor(qc, 16);
            qc += __shfl_xor(qc, 32);
            if (l < 16) sPart[w][tc][lx] = qc;
        }
        __syncthreads();
        if (t < N) {
            int b = t >> 4, x = t & 15;
            float s = sPart[0][b][x] + sPart[1][b][x] + sPart[2][b][x] + sPart[3][b][x]
                    + sPart[4][b][x] + sPart[5][b][x] + sPart[6][b][x] + sPart[7][b][x];
            sV[t] = MUF * fastrcp(s + EPSF);
        }
        __syncthreads();
    }

    // ---- phase 4: loss = sum u_i K_ij C_ij v_j (u, K, C register-resident) ----
    float vc[8];
    #pragma unroll
    for (int tc = 0; tc < 8; ++tc) vc[tc] = sV[16 * tc + lx];

    float part = 0.f;
    #pragma unroll
    for (int tc = 0; tc < 8; ++tc) {
        // unpack bf16 C: low half -> <<16, high half -> mask
        union { unsigned u; float f; } c0, c1, c2, c3;
        c0.u = ccp[tc][0] << 16;
        c1.u = ccp[tc][0] & 0xFFFF0000u;
        c2.u = ccp[tc][1] << 16;
        c3.u = ccp[tc][1] & 0xFFFF0000u;
        float rs = uu[0] * kk[tc][0] * c0.f
                 + uu[1] * kk[tc][1] * c1.f
                 + uu[2] * kk[tc][2] * c2.f
                 + uu[3] * kk[tc][3] * c3.f;
        part += rs * vc[tc];
    }

    // deterministic block reduce
    #pragma unroll
    for (int off = 32; off >= 1; off >>= 1)
        part += __shfl_xor(part, off);
    if (l == 0) sRed[w] = part;
    __syncthreads();
    if (t == 0) {
        float s = 0.f;
        #pragma unroll
        for (int i = 0; i < 8; ++i) s += sRed[i];
        lossg[bt] = s;
    }
}

// mean over 2048 per-frame losses -> d_out[0]
__global__ __launch_bounds__(256, 1)
void reduce_mean(const float* __restrict__ lossg, float* __restrict__ out)
{
    __shared__ float sRed[4];
    int t = threadIdx.x;
    float s = 0.f;
    #pragma unroll
    for (int it = 0; it < 8; ++it) s += lossg[t + 256 * it];
    #pragma unroll
    for (int off = 32; off >= 1; off >>= 1) s += __shfl_xor(s, off);
    if ((t & 63) == 0) sRed[t >> 6] = s;
    __syncthreads();
    if (t == 0) out[0] = (sRed[0] + sRed[1] + sRed[2] + sRed[3]) * (1.0f / 2048.0f);
}

extern "C" void kernel_launch(void* const* d_in, const int* in_sizes, int n_in,
                              void* d_out, int out_size, void* d_ws, size_t ws_size,
                              hipStream_t stream)
{
    const float* src = (const float*)d_in[0];
    const float* tgt = (const float*)d_in[1];
    float* ws = (float*)d_ws;                       // 2048 floats of scratch

    sinkhorn_batch<<<NBATCH, 512, 0, stream>>>(src, tgt, ws);
    reduce_mean<<<1, 256, 0, stream>>>(ws, (float*)d_out);
}

// Round 6
// 66.331 us; speedup vs baseline: 1.0791x; 1.0791x over previous
//
#include <hip/hip_runtime.h>
#include <hip/hip_bf16.h>

constexpr int NBATCH = 2048;   // B*T
constexpr int N      = 128;    // nodes
constexpr float INVTAU = 20.0f;   // 1/0.05
constexpr float EPSF   = 1e-8f;
constexpr float MUF    = 1.0f / 128.0f;   // mu = nu = 1/N

typedef __attribute__((ext_vector_type(8))) short short8;   // 8 x bf16 MFMA frag
typedef __attribute__((ext_vector_type(4))) float f32x4;    // MFMA accumulator
typedef __attribute__((ext_vector_type(2))) float f32x2;    // packed pair -> v_pk_fma_f32

static __device__ __forceinline__ float fastrcp(float x) {
    return __builtin_amdgcn_rcpf(x);    // v_rcp_f32, ~1e-7 rel err
}
static __device__ __forceinline__ float fastsqrt(float x) {
    return __builtin_amdgcn_sqrtf(x);   // raw v_sqrt_f32
}

// LDS bf16 tile, XOR-swizzled: row r, k-elt k at ushort idx
//   r*64 + (((k>>3) ^ (r&7)) << 3) + (k&7)
// 512 threads = 8 waves; wave w owns C rows 16w..16w+15, all 128 cols.
// Lane (lx=l&15, lh=l>>4) owns rows 16w+4lh+q (q<4), cols 16tc+lx (tc<8).
// K kept as f32x2 pairs over q (packed FMA); C packed bf16 (loss linear in C).
// launch_bounds(512,4): 4 waves/EU, reg cap 128 -- round 5 showed cap 85 spills
// (WRITE_SIZE 64KB -> 73MB); this config is the no-spill occupancy frontier.
__global__ __launch_bounds__(512, 4)
void sinkhorn_batch(const float* __restrict__ srcg,
                    const float* __restrict__ tgtg,
                    float* __restrict__ lossg)
{
    __shared__ ushort sA[N * 64];          // src bf16, swizzled (16 KB)
    __shared__ ushort sB[N * 64];          // tgt bf16, swizzled (16 KB)
    __shared__ float sX2[N], sY2[N], sV[N];
    __shared__ float sPart[8][8][16];      // [wave][colTile][lx] partials (4 KB)
    __shared__ float sRed[8];

    const int t  = threadIdx.x;
    const int l  = t & 63;
    const int w  = t >> 6;       // wave 0..7
    const int lx = l & 15;
    const int lh = l >> 4;       // 0..3
    const int bt = blockIdx.x;

    const float4* sg4 = reinterpret_cast<const float4*>(srcg + (size_t)bt * (N * 64));
    const float4* tg4 = reinterpret_cast<const float4*>(tgtg + (size_t)bt * (N * 64));

    // ---- phase 0: stage bf16 (swizzled) + fp32 row norms, fused butterfly ----
    #pragma unroll
    for (int it = 0; it < 4; ++it) {
        int f  = t + 512 * it;    // 0..2047 float4s; 16 consecutive lanes = one row
        int r  = f >> 4;
        int d4 = f & 15;
        float4 a = sg4[f];
        float4 b = tg4[f];
        float pa = a.x * a.x + a.y * a.y + a.z * a.z + a.w * a.w;
        float pb = b.x * b.x + b.y * b.y + b.z * b.z + b.w * b.w;
        // lanes g<8 carry pa, g>=8 carry pb (one exchange), then 8-lane tree
        float x = (lx & 8) ? pb : pa;
        float y = (lx & 8) ? pa : pb;
        x += __shfl_xor(y, 8);
        x += __shfl_xor(x, 1);
        x += __shfl_xor(x, 2);
        x += __shfl_xor(x, 4);
        if ((lx & 7) == 0) ((lx & 8) ? sY2 : sX2)[r] = x;

        int idx = r * 64 + (((d4 >> 1) ^ (r & 7)) << 3) + (d4 & 1) * 4;
        union { __hip_bfloat162 h[2]; ushort4 u; } ca, cb;
        ca.h[0] = __float22bfloat162_rn(make_float2(a.x, a.y));
        ca.h[1] = __float22bfloat162_rn(make_float2(a.z, a.w));
        cb.h[0] = __float22bfloat162_rn(make_float2(b.x, b.y));
        cb.h[1] = __float22bfloat162_rn(make_float2(b.z, b.w));
        *reinterpret_cast<ushort4*>(&sA[idx]) = ca.u;
        *reinterpret_cast<ushort4*>(&sB[idx]) = cb.u;
    }
    __syncthreads();

    // ---- phase 1+2 fused: per col-tile MFMA -> C,K (acc lives 4 regs at a time) --
    float x2r[4], y2c[8];
    #pragma unroll
    for (int q = 0; q < 4; ++q) x2r[q] = sX2[16 * w + 4 * lh + q];
    #pragma unroll
    for (int tc = 0; tc < 8; ++tc) y2c[tc] = sY2[16 * tc + lx];

    short8 af0, af1;
    {
        int ra = 16 * w + lx;
        af0 = *reinterpret_cast<const short8*>(&sA[ra * 64 + (((0 + lh) ^ (ra & 7)) << 3)]);
        af1 = *reinterpret_cast<const short8*>(&sA[ra * 64 + (((4 + lh) ^ (ra & 7)) << 3)]);
    }

    f32x2 kk2[8][2];      // kk2[tc][p] = {K[q=2p], K[q=2p+1]}
    unsigned ccp[8][2];   // packed bf16 C: (bf16(c[2p+1])<<16)|bf16(c[2p])
    #pragma unroll
    for (int tc = 0; tc < 8; ++tc) {
        int rb = 16 * tc + lx;
        short8 bf0 = *reinterpret_cast<const short8*>(&sB[rb * 64 + (((0 + lh) ^ (rb & 7)) << 3)]);
        short8 bf1 = *reinterpret_cast<const short8*>(&sB[rb * 64 + (((4 + lh) ^ (rb & 7)) << 3)]);
        f32x4 acc = (f32x4){0.f, 0.f, 0.f, 0.f};
        acc = __builtin_amdgcn_mfma_f32_16x16x32_bf16(af0, bf0, acc, 0, 0, 0);
        acc = __builtin_amdgcn_mfma_f32_16x16x32_bf16(af1, bf1, acc, 0, 0, 0);
        float cd[4];
        #pragma unroll
        for (int q = 0; q < 4; ++q) {
            float d2 = x2r[q] + y2c[tc] - 2.0f * acc[q];
            cd[q] = fastsqrt(fmaxf(d2, 0.f));
        }
        kk2[tc][0] = (f32x2){__expf(-INVTAU * cd[0]), __expf(-INVTAU * cd[1])};
        kk2[tc][1] = (f32x2){__expf(-INVTAU * cd[2]), __expf(-INVTAU * cd[3])};
        union { __hip_bfloat162 h; unsigned u; } p0, p1;
        p0.h = __float22bfloat162_rn(make_float2(cd[0], cd[1]));
        p1.h = __float22bfloat162_rn(make_float2(cd[2], cd[3]));
        ccp[tc][0] = p0.u;
        ccp[tc][1] = p1.u;
    }

    if (t < N) sV[t] = 1.0f;
    __syncthreads();

    // ---- phase 3: Sinkhorn; u register-resident, packed FMAs ----
    f32x2 uu2[2];
    for (int iter = 0; iter < 5; ++iter) {
        // u_i = mu / (sum_j K[i][j] v[j] + eps): reduce over cols (lx in-wave)
        float vv[8];
        #pragma unroll
        for (int tc = 0; tc < 8; ++tc) vv[tc] = sV[16 * tc + lx];
        f32x2 p0 = (f32x2){0.f, 0.f}, p1 = (f32x2){0.f, 0.f};
        #pragma unroll
        for (int tc = 0; tc < 8; ++tc) {
            f32x2 vb = (f32x2){vv[tc], vv[tc]};
            p0 = kk2[tc][0] * vb + p0;      // v_pk_fma_f32
            p1 = kk2[tc][1] * vb + p1;
        }
        float s0 = p0.x, s1 = p0.y, s2 = p1.x, s3 = p1.y;
        s0 += __shfl_xor(s0, 1); s1 += __shfl_xor(s1, 1); s2 += __shfl_xor(s2, 1); s3 += __shfl_xor(s3, 1);
        s0 += __shfl_xor(s0, 2); s1 += __shfl_xor(s1, 2); s2 += __shfl_xor(s2, 2); s3 += __shfl_xor(s3, 2);
        s0 += __shfl_xor(s0, 4); s1 += __shfl_xor(s1, 4); s2 += __shfl_xor(s2, 4); s3 += __shfl_xor(s3, 4);
        s0 += __shfl_xor(s0, 8); s1 += __shfl_xor(s1, 8); s2 += __shfl_xor(s2, 8); s3 += __shfl_xor(s3, 8);
        uu2[0] = (f32x2){MUF * fastrcp(s0 + EPSF), MUF * fastrcp(s1 + EPSF)};
        uu2[1] = (f32x2){MUF * fastrcp(s2 + EPSF), MUF * fastrcp(s3 + EPSF)};
        // no barrier: u never touches LDS

        // v_j = nu / (sum_i K[i][j] u[i] + eps): reduce over rows
        #pragma unroll
        for (int tc = 0; tc < 8; ++tc) {
            f32x2 t2 = kk2[tc][0] * uu2[0] + kk2[tc][1] * uu2[1];
            float qc = t2.x + t2.y;
            qc += __shfl_xor(qc, 16);
            qc += __shfl_xor(qc, 32);
            if (l < 16) sPart[w][tc][lx] = qc;
        }
        __syncthreads();
        if (t < N) {
            int b = t >> 4, x = t & 15;
            float s = sPart[0][b][x] + sPart[1][b][x] + sPart[2][b][x] + sPart[3][b][x]
                    + sPart[4][b][x] + sPart[5][b][x] + sPart[6][b][x] + sPart[7][b][x];
            sV[t] = MUF * fastrcp(s + EPSF);
        }
        __syncthreads();
    }

    // ---- phase 4: loss = sum u_i K_ij C_ij v_j (u, K, C register-resident) ----
    float vc[8];
    #pragma unroll
    for (int tc = 0; tc < 8; ++tc) vc[tc] = sV[16 * tc + lx];

    float part = 0.f;
    #pragma unroll
    for (int tc = 0; tc < 8; ++tc) {
        union { unsigned u; float f; } e0, e1, e2, e3;
        e0.u = ccp[tc][0] << 16;
        e1.u = ccp[tc][0] & 0xFFFF0000u;
        e2.u = ccp[tc][1] << 16;
        e3.u = ccp[tc][1] & 0xFFFF0000u;
        f32x2 c0 = (f32x2){e0.f, e1.f};
        f32x2 c1 = (f32x2){e2.f, e3.f};
        f32x2 r2 = uu2[0] * kk2[tc][0] * c0 + uu2[1] * kk2[tc][1] * c1;
        part += (r2.x + r2.y) * vc[tc];
    }

    // deterministic block reduce
    #pragma unroll
    for (int off = 32; off >= 1; off >>= 1)
        part += __shfl_xor(part, off);
    if (l == 0) sRed[w] = part;
    __syncthreads();
    if (t == 0) {
        float s = 0.f;
        #pragma unroll
        for (int i = 0; i < 8; ++i) s += sRed[i];
        lossg[bt] = s;
    }
}

// mean over 2048 per-frame losses -> d_out[0]
__global__ __launch_bounds__(256, 1)
void reduce_mean(const float* __restrict__ lossg, float* __restrict__ out)
{
    __shared__ float sRed[4];
    int t = threadIdx.x;
    float s = 0.f;
    #pragma unroll
    for (int it = 0; it < 8; ++it) s += lossg[t + 256 * it];
    #pragma unroll
    for (int off = 32; off >= 1; off >>= 1) s += __shfl_xor(s, off);
    if ((t & 63) == 0) sRed[t >> 6] = s;
    __syncthreads();
    if (t == 0) out[0] = (sRed[0] + sRed[1] + sRed[2] + sRed[3]) * (1.0f / 2048.0f);
}

extern "C" void kernel_launch(void* const* d_in, const int* in_sizes, int n_in,
                              void* d_out, int out_size, void* d_ws, size_t ws_size,
                              hipStream_t stream)
{
    const float* src = (const float*)d_in[0];
    const float* tgt = (const float*)d_in[1];
    float* ws = (float*)d_ws;                       // 2048 floats of scratch

    sinkhorn_batch<<<NBATCH, 512, 0, stream>>>(src, tgt, ws);
    reduce_mean<<<1, 256, 0, stream>>>(ws, (float*)d_out);
}